// Round 1
// 1974.240 us; speedup vs baseline: 1.4541x; 1.4541x over previous
//
#include <hip/hip_runtime.h>

// ---------------------------------------------------------------------------
// FoveaModel forward on MI355X (gfx950). All tensors are float32 (reference
// dtype). Pipeline (all on `stream`, sequential ordering gives dependencies):
//   1. mask    : fovea (= x*mask) and hr (= x*patch) -> d_out
//   2. lstm1   : conv([fovea,h1], w1)+gates -> h1n, c1n
//   3. lstm2   : conv([h1n,  h2], w2)+gates -> h2n, c2n   (2 gate-groups/tile)
//   4. lstm3   : conv([h2n,  h3], w3)+gates -> h3n, c3n, hidden(copy)
//   5. recon   : conv(h3n, wc)+bc -> reconstruction
// Later stages read earlier f32 outputs straight from d_out.
//
// R1 change: chunked LDS staging of input channels. LDS per block was
// CIN*630*4 B (lstm2: 60.5 KiB -> 2 blocks/CU, 2 waves/SIMD; latency-bound,
// VALUBusy 45%). Staging CHUNK channels at a time (lstm2: 12 -> 30.2 KiB,
// lstm3: 10 -> 25.2 KiB) doubles resident blocks to the VGPR cap
// (88 VGPR -> 4 waves/SIMD), so TLP covers the lgkm (weight s_load +
// neighborhood ds_read) waits. Same global traffic, +2 barriers per chunk.
// ---------------------------------------------------------------------------

#define NN 224
#define SS (224 * 224)
#define BB 32

// tile geometry: 32 wide x 16 tall, 256 threads, 2 adjacent px per thread
#define TW 32
#define TH 16
#define LDS_RS 35              // padded row stride (odd -> <=2 lanes/bank, free)
#define LDS_CS (18 * LDS_RS)   // 630 floats per channel (18 halo rows)

__device__ __forceinline__ float fsigmoid(float x) {
    return __fdividef(1.f, 1.f + __expf(-x));
}
__device__ __forceinline__ float ftanh(float x) {
    return __fdividef(2.f, 1.f + __expf(-2.f * x)) - 1.f;
}

__device__ __forceinline__ void store_f2(float* p, float a, float b) {
    *reinterpret_cast<float2*>(p) = make_float2(a, b);   // p is 8B aligned
}

// ---------------------------------------------------------------------------
// 1. mask kernel: fovea = x * ((rand>0.95)|patch), hr = x * patch
// ---------------------------------------------------------------------------
__global__ __launch_bounds__(256) void mask_kernel(
    const float* __restrict__ x,
    const float* __restrict__ rmask,
    const int* __restrict__ samples,
    float* __restrict__ fovea,
    float* __restrict__ hr)
{
    int idx = blockIdx.x * 256 + threadIdx.x;          // b*S + p
    if (idx >= BB * SS) return;
    int b = idx / SS;
    int p = idx - b * SS;
    int y = p / NN;
    int xx = p - y * NN;
    int s = samples[b];
    int px = s / 7, py = s - px * 7;
    bool patch = (y >= px * 32) && (y < px * 32 + 32) &&
                 (xx >= py * 32) && (xx < py * 32 + 32);
    bool m = (rmask[idx] > 0.95f) || patch;
#pragma unroll
    for (int c = 0; c < 3; ++c) {
        size_t o = ((size_t)b * 3 + c) * SS + p;
        float xv = x[o];
        fovea[o] = m ? xv : 0.f;
        hr[o]    = patch ? xv : 0.f;
    }
}

// ---------------------------------------------------------------------------
// 2-4. ConvLSTM step: z = conv3x3([xin,hin], w)+b ; gates ; (h,c) out
// CIN1 channels from xin, CIN2 from hin. CG = per-gate channels (Cout = 4*CG).
// GROUPS gate-consistent channel groups per tile (blockIdx.z).
// CHUNK input channels staged in LDS at a time (controls LDS footprint /
// occupancy: LDS bytes = CHUNK*630*4; keep <= ~30 KiB for 4 blocks/CU).
// ---------------------------------------------------------------------------
template <int CIN1, int CIN2, int CG, int GROUPS, int CHUNK>
__global__ __launch_bounds__(256, 4) void convlstm_kernel(
    const float* __restrict__ xin,
    const float* __restrict__ hin,
    const float* __restrict__ cin,
    const float* __restrict__ w,      // [4*CG][CIN][3][3]
    const float* __restrict__ bias,   // [4*CG]
    float* __restrict__ hout,
    float* __restrict__ cout_,
    float* __restrict__ hout2)        // optional second copy of h (hidden)
{
    constexpr int CIN = CIN1 + CIN2;
    constexpr int CGB = CG / GROUPS;  // gate-channels this block computes
    constexpr int NCO = 4 * CGB;      // conv output channels this block computes

    __shared__ float lds[CHUNK * LDS_CS];

    const int tid = threadIdx.x;
    const int tileId = blockIdx.x;            // 0..97
    const int tx0 = (tileId % 7) * TW;
    const int ty0 = (tileId / 7) * TH;
    const int b = blockIdx.y;
    const int cg0 = blockIdx.z * CGB;

    const int tx2 = tid & 15;   // pixel-pair column index
    const int ty = tid >> 4;    // 0..15
    const int lx = 2 * tx2;     // local x of first pixel

    float accx[NCO], accy[NCO];
#pragma unroll
    for (int g = 0; g < NCO; ++g) {
        int q = g / CGB, j = g - q * CGB;
        float bv = bias[q * CG + cg0 + j];
        accx[g] = bv;
        accy[g] = bv;
    }

    for (int cc = 0; cc < CIN; cc += CHUNK) {
        const int CL = (CIN - cc) < CHUNK ? (CIN - cc) : CHUNK;

        // ---- stage CL input channels (with halo, zero-padded) into LDS ----
        if (cc) __syncthreads();           // prior chunk's compute must finish
        const int TOT = CL * (18 * 34);
        for (int idx = tid; idx < TOT; idx += 256) {
            int ci = idx / (18 * 34);      // chunk-local channel
            int r = idx - ci * (18 * 34);
            int row = r / 34;
            int col = r - row * 34;
            int gy = ty0 + row - 1;
            int gx = tx0 + col - 1;
            int gc = cc + ci;              // global input channel
            float v = 0.f;
            if ((unsigned)gy < NN && (unsigned)gx < NN) {
                const float* src = (gc < CIN1)
                    ? xin + ((size_t)b * CIN1 + gc) * SS
                    : hin + ((size_t)b * CIN2 + (gc - CIN1)) * SS;
                v = src[gy * NN + gx];
            }
            lds[ci * LDS_CS + row * LDS_RS + col] = v;
        }
        __syncthreads();

        // ---- accumulate this chunk ----
#pragma unroll 1
        for (int ci = 0; ci < CL; ++ci) {
            // 3 rows x 4 cols neighborhood for the pixel pair
            float n[3][4];
            const float* lrow = &lds[ci * LDS_CS + ty * LDS_RS + lx];
#pragma unroll
            for (int dy = 0; dy < 3; ++dy)
#pragma unroll
                for (int dx = 0; dx < 4; ++dx)
                    n[dy][dx] = lrow[dy * LDS_RS + dx];

#pragma unroll
            for (int g = 0; g < NCO; ++g) {
                int q = g / CGB, j = g - q * CGB;
                int co = q * CG + cg0 + j;                    // block-uniform
                const float* wr = &w[((size_t)co * CIN + cc + ci) * 9];
                float ax = accx[g], ay = accy[g];
#pragma unroll
                for (int dy = 0; dy < 3; ++dy) {
#pragma unroll
                    for (int dx = 0; dx < 3; ++dx) {
                        float wv = wr[dy * 3 + dx];           // uniform -> s_load
                        ax += wv * n[dy][dx];
                        ay += wv * n[dy][dx + 1];
                    }
                }
                accx[g] = ax;
                accy[g] = ay;
            }
        }
    }

    // ---- gates + state update, write f32 pairs ----
    const int gy = ty0 + ty;
    const int gx = tx0 + lx;
#pragma unroll
    for (int j = 0; j < CGB; ++j) {
        int cch = cg0 + j;
        size_t base = ((size_t)b * CG + cch) * SS + (size_t)gy * NN + gx;
        float2 cv = *reinterpret_cast<const float2*>(&cin[base]);
        float i0 = fsigmoid(accx[0 * CGB + j]), i1 = fsigmoid(accy[0 * CGB + j]);
        float f0 = fsigmoid(accx[1 * CGB + j]), f1 = fsigmoid(accy[1 * CGB + j]);
        float o0 = fsigmoid(accx[2 * CGB + j]), o1 = fsigmoid(accy[2 * CGB + j]);
        float g0 = ftanh(accx[3 * CGB + j]),    g1 = ftanh(accy[3 * CGB + j]);
        float cn0 = f0 * cv.x + i0 * g0;
        float cn1 = f1 * cv.y + i1 * g1;
        float h0 = o0 * ftanh(cn0);
        float h1 = o1 * ftanh(cn1);
        store_f2(&cout_[base], cn0, cn1);
        store_f2(&hout[base], h0, h1);
        if (hout2) store_f2(&hout2[base], h0, h1);
    }
}

// ---------------------------------------------------------------------------
// 5. plain 3x3 conv (reconstruction): 3 -> 3 channels
// ---------------------------------------------------------------------------
__global__ __launch_bounds__(256) void conv_plain_kernel(
    const float* __restrict__ in,
    const float* __restrict__ w,      // [3][3][3][3]
    const float* __restrict__ bias,   // [3]
    float* __restrict__ out)
{
    constexpr int CIN = 3, NCO = 3;
    __shared__ float lds[CIN * LDS_CS];

    const int tid = threadIdx.x;
    const int tileId = blockIdx.x;
    const int tx0 = (tileId % 7) * TW;
    const int ty0 = (tileId / 7) * TH;
    const int b = blockIdx.y;

    const int TOT = CIN * 18 * 34;
    for (int idx = tid; idx < TOT; idx += 256) {
        int ci = idx / (18 * 34);
        int r = idx - ci * (18 * 34);
        int row = r / 34;
        int col = r - row * 34;
        int gy = ty0 + row - 1;
        int gx = tx0 + col - 1;
        float v = 0.f;
        if ((unsigned)gy < NN && (unsigned)gx < NN)
            v = in[((size_t)b * CIN + ci) * SS + gy * NN + gx];
        lds[ci * LDS_CS + row * LDS_RS + col] = v;
    }
    __syncthreads();

    const int tx2 = tid & 15;
    const int ty = tid >> 4;
    const int lx = 2 * tx2;

    float accx[NCO], accy[NCO];
#pragma unroll
    for (int g = 0; g < NCO; ++g) { accx[g] = bias[g]; accy[g] = bias[g]; }

#pragma unroll
    for (int ci = 0; ci < CIN; ++ci) {
        float n[3][4];
        const float* lrow = &lds[ci * LDS_CS + ty * LDS_RS + lx];
#pragma unroll
        for (int dy = 0; dy < 3; ++dy)
#pragma unroll
            for (int dx = 0; dx < 4; ++dx)
                n[dy][dx] = lrow[dy * LDS_RS + dx];
#pragma unroll
        for (int g = 0; g < NCO; ++g) {
            const float* wr = &w[((size_t)g * CIN + ci) * 9];
            float ax = accx[g], ay = accy[g];
#pragma unroll
            for (int dy = 0; dy < 3; ++dy)
#pragma unroll
                for (int dx = 0; dx < 3; ++dx) {
                    float wv = wr[dy * 3 + dx];
                    ax += wv * n[dy][dx];
                    ay += wv * n[dy][dx + 1];
                }
            accx[g] = ax;
            accy[g] = ay;
        }
    }

    const int gy = ty0 + ty;
    const int gx = tx0 + lx;
#pragma unroll
    for (int g = 0; g < NCO; ++g) {
        size_t base = ((size_t)b * NCO + g) * SS + (size_t)gy * NN + gx;
        store_f2(&out[base], accx[g], accy[g]);
    }
}

// ---------------------------------------------------------------------------
extern "C" void kernel_launch(void* const* d_in, const int* in_sizes, int n_in,
                              void* d_out, int out_size, void* d_ws, size_t ws_size,
                              hipStream_t stream)
{
    (void)in_sizes; (void)n_in; (void)out_size; (void)d_ws; (void)ws_size;

    const float* x     = (const float*)d_in[0];
    const float* h1    = (const float*)d_in[2];
    const float* c1    = (const float*)d_in[3];
    const float* h2    = (const float*)d_in[4];
    const float* c2    = (const float*)d_in[5];
    const float* h3    = (const float*)d_in[6];
    const float* c3    = (const float*)d_in[7];
    const float* rmask = (const float*)d_in[8];
    const int* samples = (const int*)d_in[9];
    const float* W1    = (const float*)d_in[10];
    const float* B1    = (const float*)d_in[11];
    const float* W2    = (const float*)d_in[12];
    const float* B2    = (const float*)d_in[13];
    const float* W3    = (const float*)d_in[14];
    const float* B3    = (const float*)d_in[15];
    const float* WC    = (const float*)d_in[16];
    const float* BC    = (const float*)d_in[17];

    float* out = (float*)d_out;
    // output offsets (elements, reference return order)
    float* h1n    = out + 0;
    float* c1n    = out + 12845056;
    float* h2n    = out + 25690112;
    float* c2n    = out + 51380224;
    float* h3n    = out + 77070336;
    float* c3n    = out + 81887232;
    float* recon  = out + 86704128;
    float* fovea  = out + 91521024;
    float* hr     = out + 96337920;
    float* hidden = out + 101154816;

    mask_kernel<<<(BB * SS + 255) / 256, 256, 0, stream>>>(x, rmask, samples, fovea, hr);

    // lstm1: CIN=11, LDS 27.7 KiB (single chunk) -> already 4 blocks/CU
    convlstm_kernel<3, 8, 8, 1, 11><<<dim3(98, BB, 1), 256, 0, stream>>>(
        fovea, h1, c1, W1, B1, h1n, c1n, nullptr);

    // lstm2: CIN=24, CHUNK=12 -> 30.2 KiB -> 4 blocks/CU (was 60.5 KiB / 2)
    convlstm_kernel<8, 16, 16, 2, 12><<<dim3(98, BB, 2), 256, 0, stream>>>(
        h1n, h2, c2, W2, B2, h2n, c2n, nullptr);

    // lstm3: CIN=19, CHUNK=10 -> 25.2 KiB -> 4 blocks/CU (was 47.9 KiB / 3)
    convlstm_kernel<16, 3, 3, 1, 10><<<dim3(98, BB, 1), 256, 0, stream>>>(
        h2n, h3, c3, W3, B3, h3n, c3n, hidden);

    conv_plain_kernel<<<dim3(98, BB, 1), 256, 0, stream>>>(h3n, WC, BC, recon);
}

// Round 2
// 1397.299 us; speedup vs baseline: 2.0545x; 1.4129x over previous
//
#include <hip/hip_runtime.h>

// ---------------------------------------------------------------------------
// FoveaModel forward on MI355X (gfx950). All tensors are float32 (reference
// dtype). Pipeline (all on `stream`, sequential ordering gives dependencies):
//   0. wtrans  : transpose conv weights [co][ci][3][3] -> wt[ci][tap][co] (d_ws)
//   1. mask    : fovea (= x*mask) and hr (= x*patch) -> d_out
//   2. lstm1   : conv([fovea,h1], w1)+gates -> h1n, c1n
//   3. lstm2   : conv([h1n,  h2], w2)+gates -> h2n, c2n   (2 gate-groups/tile)
//   4. lstm3   : conv([h2n,  h3], w3)+gates -> h3n, c3n, hidden(copy)
//   5. recon   : conv(h3n, wc)+bc -> reconstruction
//
// R1: chunked LDS staging -> 4 blocks/CU (occupancy 23->44%, 2870->1974 us).
// R2: packed-fp32 inner loop (v_pk_fma_f32). Pack adjacent OUTPUT CHANNELS:
//     acc pair (co,co+1) updated by one pk-FMA with a weight pair (contiguous
//     in the transposed wt layout -> uniform s_load_dwordx2) times a splatted
//     LDS neighborhood value (splat amortized over NCO/2 channel pairs).
//     Halves the dominant VALU instruction class; math stays exact fp32.
// ---------------------------------------------------------------------------

#define NN 224
#define SS (224 * 224)
#define BB 32

// tile geometry: 32 wide x 16 tall, 256 threads, 2 adjacent px per thread
#define TW 32
#define TH 16
#define LDS_RS 35              // padded row stride (odd -> <=2 lanes/bank, free)
#define LDS_CS (18 * LDS_RS)   // 630 floats per channel (18 halo rows)

typedef float v2f __attribute__((ext_vector_type(2)));

__device__ __forceinline__ float fsigmoid(float x) {
    return __fdividef(1.f, 1.f + __expf(-x));
}
__device__ __forceinline__ float ftanh(float x) {
    return __fdividef(2.f, 1.f + __expf(-2.f * x)) - 1.f;
}

__device__ __forceinline__ void store_f2(float* p, float a, float b) {
    *reinterpret_cast<float2*>(p) = make_float2(a, b);   // p is 8B aligned
}

// ---------------------------------------------------------------------------
// 0. weight transpose: w[co][ci][3][3] -> wt[ci][tap][co]  (co contiguous)
// ---------------------------------------------------------------------------
__device__ __forceinline__ void wtrans_one(const float* __restrict__ w,
                                           float* __restrict__ wt,
                                           int COUT, int CIN, int idx)
{
    int co = idx / (CIN * 9);
    int r = idx - co * (CIN * 9);
    int ci = r / 9;
    int tap = r - ci * 9;
    wt[(ci * 9 + tap) * COUT + co] = w[idx];
}

#define WT1_N (32 * 11 * 9)   // 3168
#define WT2_N (64 * 24 * 9)   // 13824
#define WT3_N (12 * 19 * 9)   // 2052
#define WT1_OFF 0
#define WT2_OFF WT1_N
#define WT3_OFF (WT1_N + WT2_N)

__global__ __launch_bounds__(256) void wtrans_kernel(
    const float* __restrict__ w1,
    const float* __restrict__ w2,
    const float* __restrict__ w3,
    float* __restrict__ wt)
{
    int idx = blockIdx.x * 256 + threadIdx.x;
    if (idx < WT1_N) {
        wtrans_one(w1, wt + WT1_OFF, 32, 11, idx);
    } else if (idx < WT1_N + WT2_N) {
        wtrans_one(w2, wt + WT2_OFF, 64, 24, idx - WT1_N);
    } else if (idx < WT1_N + WT2_N + WT3_N) {
        wtrans_one(w3, wt + WT3_OFF, 12, 19, idx - WT1_N - WT2_N);
    }
}

// ---------------------------------------------------------------------------
// 1. mask kernel: fovea = x * ((rand>0.95)|patch), hr = x * patch
// ---------------------------------------------------------------------------
__global__ __launch_bounds__(256) void mask_kernel(
    const float* __restrict__ x,
    const float* __restrict__ rmask,
    const int* __restrict__ samples,
    float* __restrict__ fovea,
    float* __restrict__ hr)
{
    int idx = blockIdx.x * 256 + threadIdx.x;          // b*S + p
    if (idx >= BB * SS) return;
    int b = idx / SS;
    int p = idx - b * SS;
    int y = p / NN;
    int xx = p - y * NN;
    int s = samples[b];
    int px = s / 7, py = s - px * 7;
    bool patch = (y >= px * 32) && (y < px * 32 + 32) &&
                 (xx >= py * 32) && (xx < py * 32 + 32);
    bool m = (rmask[idx] > 0.95f) || patch;
#pragma unroll
    for (int c = 0; c < 3; ++c) {
        size_t o = ((size_t)b * 3 + c) * SS + p;
        float xv = x[o];
        fovea[o] = m ? xv : 0.f;
        hr[o]    = patch ? xv : 0.f;
    }
}

// ---------------------------------------------------------------------------
// 2-4. ConvLSTM step: z = conv3x3([xin,hin], wt)+b ; gates ; (h,c) out
// CIN1 channels from xin, CIN2 from hin. CG = per-gate channels (Cout = 4*CG).
// GROUPS gate-consistent channel groups per tile (blockIdx.z).
// CHUNK input channels staged in LDS at a time (LDS = CHUNK*630*4 B).
// Weights come pre-transposed: wt[ci][tap][co], co contiguous -> channel-pair
// packed fp32 FMAs (v_pk_fma_f32). Requires NCO even, and co(g+1)==co(g)+1
// for even g (true when CGB even, or GROUPS==1).
// ---------------------------------------------------------------------------
template <int CIN1, int CIN2, int CG, int GROUPS, int CHUNK>
__global__ __launch_bounds__(256, 4) void convlstm_kernel(
    const float* __restrict__ xin,
    const float* __restrict__ hin,
    const float* __restrict__ cin,
    const float* __restrict__ wt,     // [CIN][9][COUT] transposed weights
    const float* __restrict__ bias,   // [4*CG]
    float* __restrict__ hout,
    float* __restrict__ cout_,
    float* __restrict__ hout2)        // optional second copy of h (hidden)
{
    constexpr int CIN = CIN1 + CIN2;
    constexpr int COUT = 4 * CG;      // total conv output channels
    constexpr int CGB = CG / GROUPS;  // gate-channels this block computes
    constexpr int NCO = 4 * CGB;      // conv output channels this block computes
    constexpr int NCO2 = NCO / 2;     // channel pairs
    static_assert((CGB % 2 == 0) || (GROUPS == 1), "channel pairing invalid");

    __shared__ float lds[CHUNK * LDS_CS];

    const int tid = threadIdx.x;
    const int tileId = blockIdx.x;            // 0..97
    const int tx0 = (tileId % 7) * TW;
    const int ty0 = (tileId / 7) * TH;
    const int b = blockIdx.y;
    const int cg0 = blockIdx.z * CGB;

    const int tx2 = tid & 15;   // pixel-pair column index
    const int ty = tid >> 4;    // 0..15
    const int lx = 2 * tx2;     // local x of first pixel

    // accp[pp][pix] = (acc[co(2pp)], acc[co(2pp)+1]) for pixel pix
    v2f accp[NCO2][2];
#pragma unroll
    for (int pp = 0; pp < NCO2; ++pp) {
        int g = 2 * pp;
        int q = g / CGB, j = g - q * CGB;
        int co = q * CG + cg0 + j;
        v2f bv = { bias[co], bias[co + 1] };
        accp[pp][0] = bv;
        accp[pp][1] = bv;
    }

    for (int cc = 0; cc < CIN; cc += CHUNK) {
        const int CL = (CIN - cc) < CHUNK ? (CIN - cc) : CHUNK;

        // ---- stage CL input channels (with halo, zero-padded) into LDS ----
        if (cc) __syncthreads();           // prior chunk's compute must finish
        const int TOT = CL * (18 * 34);
        for (int idx = tid; idx < TOT; idx += 256) {
            int ci = idx / (18 * 34);      // chunk-local channel
            int r = idx - ci * (18 * 34);
            int row = r / 34;
            int col = r - row * 34;
            int gy = ty0 + row - 1;
            int gx = tx0 + col - 1;
            int gc = cc + ci;              // global input channel
            float v = 0.f;
            if ((unsigned)gy < NN && (unsigned)gx < NN) {
                const float* src = (gc < CIN1)
                    ? xin + ((size_t)b * CIN1 + gc) * SS
                    : hin + ((size_t)b * CIN2 + (gc - CIN1)) * SS;
                v = src[gy * NN + gx];
            }
            lds[ci * LDS_CS + row * LDS_RS + col] = v;
        }
        __syncthreads();

        // ---- accumulate this chunk (channel-pair packed fp32) ----
#pragma unroll 1
        for (int ci = 0; ci < CL; ++ci) {
            // 3 rows x 4 cols neighborhood for the pixel pair
            float n[3][4];
            const float* lrow = &lds[ci * LDS_CS + ty * LDS_RS + lx];
#pragma unroll
            for (int dy = 0; dy < 3; ++dy)
#pragma unroll
                for (int dx = 0; dx < 4; ++dx)
                    n[dy][dx] = lrow[dy * LDS_RS + dx];

            // splats (backend folds into op_sel or 1 v_mov each; reused NCO2x)
            v2f sp[3][4];
#pragma unroll
            for (int dy = 0; dy < 3; ++dy)
#pragma unroll
                for (int dx = 0; dx < 4; ++dx)
                    sp[dy][dx] = (v2f){ n[dy][dx], n[dy][dx] };

            const float* wrow = wt + (size_t)(cc + ci) * (9 * COUT);
#pragma unroll
            for (int pp = 0; pp < NCO2; ++pp) {
                int g = 2 * pp;
                int q = g / CGB, j = g - q * CGB;
                int co = q * CG + cg0 + j;                // block-uniform, even
                const float* wp = wrow + co;
                v2f a0 = accp[pp][0];
                v2f a1 = accp[pp][1];
#pragma unroll
                for (int dy = 0; dy < 3; ++dy) {
#pragma unroll
                    for (int dx = 0; dx < 3; ++dx) {
                        v2f wv = *reinterpret_cast<const v2f*>(wp + (dy * 3 + dx) * COUT);
                        a0 = __builtin_elementwise_fma(wv, sp[dy][dx],     a0);
                        a1 = __builtin_elementwise_fma(wv, sp[dy][dx + 1], a1);
                    }
                }
                accp[pp][0] = a0;
                accp[pp][1] = a1;
            }
        }
    }

    // ---- gates + state update, write f32 pairs ----
#define AX(g) accp[(g) >> 1][0][(g) & 1]
#define AY(g) accp[(g) >> 1][1][(g) & 1]
    const int gy = ty0 + ty;
    const int gx = tx0 + lx;
#pragma unroll
    for (int j = 0; j < CGB; ++j) {
        int cch = cg0 + j;
        size_t base = ((size_t)b * CG + cch) * SS + (size_t)gy * NN + gx;
        float2 cv = *reinterpret_cast<const float2*>(&cin[base]);
        float i0 = fsigmoid(AX(0 * CGB + j)), i1 = fsigmoid(AY(0 * CGB + j));
        float f0 = fsigmoid(AX(1 * CGB + j)), f1 = fsigmoid(AY(1 * CGB + j));
        float o0 = fsigmoid(AX(2 * CGB + j)), o1 = fsigmoid(AY(2 * CGB + j));
        float g0 = ftanh(AX(3 * CGB + j)),    g1 = ftanh(AY(3 * CGB + j));
        float cn0 = f0 * cv.x + i0 * g0;
        float cn1 = f1 * cv.y + i1 * g1;
        float h0 = o0 * ftanh(cn0);
        float h1 = o1 * ftanh(cn1);
        store_f2(&cout_[base], cn0, cn1);
        store_f2(&hout[base], h0, h1);
        if (hout2) store_f2(&hout2[base], h0, h1);
    }
#undef AX
#undef AY
}

// ---------------------------------------------------------------------------
// 5. plain 3x3 conv (reconstruction): 3 -> 3 channels
// ---------------------------------------------------------------------------
__global__ __launch_bounds__(256) void conv_plain_kernel(
    const float* __restrict__ in,
    const float* __restrict__ w,      // [3][3][3][3]
    const float* __restrict__ bias,   // [3]
    float* __restrict__ out)
{
    constexpr int CIN = 3, NCO = 3;
    __shared__ float lds[CIN * LDS_CS];

    const int tid = threadIdx.x;
    const int tileId = blockIdx.x;
    const int tx0 = (tileId % 7) * TW;
    const int ty0 = (tileId / 7) * TH;
    const int b = blockIdx.y;

    const int TOT = CIN * 18 * 34;
    for (int idx = tid; idx < TOT; idx += 256) {
        int ci = idx / (18 * 34);
        int r = idx - ci * (18 * 34);
        int row = r / 34;
        int col = r - row * 34;
        int gy = ty0 + row - 1;
        int gx = tx0 + col - 1;
        float v = 0.f;
        if ((unsigned)gy < NN && (unsigned)gx < NN)
            v = in[((size_t)b * CIN + ci) * SS + gy * NN + gx];
        lds[ci * LDS_CS + row * LDS_RS + col] = v;
    }
    __syncthreads();

    const int tx2 = tid & 15;
    const int ty = tid >> 4;
    const int lx = 2 * tx2;

    float accx[NCO], accy[NCO];
#pragma unroll
    for (int g = 0; g < NCO; ++g) { accx[g] = bias[g]; accy[g] = bias[g]; }

#pragma unroll
    for (int ci = 0; ci < CIN; ++ci) {
        float n[3][4];
        const float* lrow = &lds[ci * LDS_CS + ty * LDS_RS + lx];
#pragma unroll
        for (int dy = 0; dy < 3; ++dy)
#pragma unroll
            for (int dx = 0; dx < 4; ++dx)
                n[dy][dx] = lrow[dy * LDS_RS + dx];
#pragma unroll
        for (int g = 0; g < NCO; ++g) {
            const float* wr = &w[((size_t)g * CIN + ci) * 9];
            float ax = accx[g], ay = accy[g];
#pragma unroll
            for (int dy = 0; dy < 3; ++dy)
#pragma unroll
                for (int dx = 0; dx < 3; ++dx) {
                    float wv = wr[dy * 3 + dx];
                    ax += wv * n[dy][dx];
                    ay += wv * n[dy][dx + 1];
                }
            accx[g] = ax;
            accy[g] = ay;
        }
    }

    const int gy = ty0 + ty;
    const int gx = tx0 + lx;
#pragma unroll
    for (int g = 0; g < NCO; ++g) {
        size_t base = ((size_t)b * NCO + g) * SS + (size_t)gy * NN + gx;
        store_f2(&out[base], accx[g], accy[g]);
    }
}

// ---------------------------------------------------------------------------
extern "C" void kernel_launch(void* const* d_in, const int* in_sizes, int n_in,
                              void* d_out, int out_size, void* d_ws, size_t ws_size,
                              hipStream_t stream)
{
    (void)in_sizes; (void)n_in; (void)out_size; (void)ws_size;

    const float* x     = (const float*)d_in[0];
    const float* h1    = (const float*)d_in[2];
    const float* c1    = (const float*)d_in[3];
    const float* h2    = (const float*)d_in[4];
    const float* c2    = (const float*)d_in[5];
    const float* h3    = (const float*)d_in[6];
    const float* c3    = (const float*)d_in[7];
    const float* rmask = (const float*)d_in[8];
    const int* samples = (const int*)d_in[9];
    const float* W1    = (const float*)d_in[10];
    const float* B1    = (const float*)d_in[11];
    const float* W2    = (const float*)d_in[12];
    const float* B2    = (const float*)d_in[13];
    const float* W3    = (const float*)d_in[14];
    const float* B3    = (const float*)d_in[15];
    const float* WC    = (const float*)d_in[16];
    const float* BC    = (const float*)d_in[17];

    float* out = (float*)d_out;
    // output offsets (elements, reference return order)
    float* h1n    = out + 0;
    float* c1n    = out + 12845056;
    float* h2n    = out + 25690112;
    float* c2n    = out + 51380224;
    float* h3n    = out + 77070336;
    float* c3n    = out + 81887232;
    float* recon  = out + 86704128;
    float* fovea  = out + 91521024;
    float* hr     = out + 96337920;
    float* hidden = out + 101154816;

    float* wtbuf = (float*)d_ws;      // 19044 floats = 76 KB

    wtrans_kernel<<<(WT1_N + WT2_N + WT3_N + 255) / 256, 256, 0, stream>>>(
        W1, W2, W3, wtbuf);

    mask_kernel<<<(BB * SS + 255) / 256, 256, 0, stream>>>(x, rmask, samples, fovea, hr);

    // lstm1: CIN=11, LDS 27.7 KiB (single chunk)
    convlstm_kernel<3, 8, 8, 1, 11><<<dim3(98, BB, 1), 256, 0, stream>>>(
        fovea, h1, c1, wtbuf + WT1_OFF, B1, h1n, c1n, nullptr);

    // lstm2: CIN=24, CHUNK=12 -> 30.2 KiB -> 4 blocks/CU
    convlstm_kernel<8, 16, 16, 2, 12><<<dim3(98, BB, 2), 256, 0, stream>>>(
        h1n, h2, c2, wtbuf + WT2_OFF, B2, h2n, c2n, nullptr);

    // lstm3: CIN=19, CHUNK=10 -> 25.2 KiB -> 4 blocks/CU
    convlstm_kernel<16, 3, 3, 1, 10><<<dim3(98, BB, 1), 256, 0, stream>>>(
        h2n, h3, c3, wtbuf + WT3_OFF, B3, h3n, c3n, hidden);

    conv_plain_kernel<<<dim3(98, BB, 1), 256, 0, stream>>>(h3n, WC, BC, recon);
}

// Round 4
// 1054.267 us; speedup vs baseline: 2.7230x; 1.3254x over previous
//
#include <hip/hip_runtime.h>

// ---------------------------------------------------------------------------
// FoveaModel forward on MI355X (gfx950).
// R3 (resubmit after infra failure): ConvLSTM conv on the matrix pipe
// (mfma_f32_16x16x32_f16, fp32 accumulate). 3x3 conv = 9 shifted GEMMs over
// K=CIN (padded to 32).
//   - LDS input tile channel-last, k-blocked: [4 kb][340 pix][8 f16]
//     (B-frag = 1 ds_read_b128: lane reads 8 contig K at pix=lane&15 — the
//      m97-verified operand pattern).
//   - Weights pre-packed (wtrans) to A-frag layout wA[tap][co'][32] f16 with
//     gate-interleaved rows co' = cell*4 + gate, so D rows (lane>>4)*4+reg
//     give each lane i,f,o,g of ONE cell -> register-local gate epilogue.
//   - D layout (m89-verified): col = lane&15 (pixel), row = (lane>>4)*4+reg.
// Pipeline: wtrans, mask, lstm1, lstm2, lstm3, recon (sequential on stream).
// ---------------------------------------------------------------------------

#define NN 224
#define SS (224 * 224)
#define BB 32

typedef _Float16 h8 __attribute__((ext_vector_type(8)));
typedef float f4 __attribute__((ext_vector_type(4)));

// lstm tile: 32 wide x 8 tall; halo tile 10 rows x 34 cols = 340 px
#define TWL 32
#define THL 8
#define HPIX 340

// recon (VALU) tile constants — unchanged from R2
#define TW 32
#define TH 16
#define LDS_RS 35
#define LDS_CS (18 * LDS_RS)

__device__ __forceinline__ float fsigmoid(float x) {
    return __fdividef(1.f, 1.f + __expf(-x));
}
__device__ __forceinline__ float ftanh(float x) {
    return __fdividef(2.f, 1.f + __expf(-2.f * x)) - 1.f;
}
__device__ __forceinline__ void store_f2(float* p, float a, float b) {
    *reinterpret_cast<float2*>(p) = make_float2(a, b);
}

// ---------------------------------------------------------------------------
// 0. weight pack: w[co=gate*CG+cell][ci][3][3] f32 ->
//    wA[t][co'=cell*4+gate][k:32] f16 (zeros for k>=CIN or cell>=CG)
//    bA[co'] f32 (gate-interleaved bias, zeros on pad rows)
// ---------------------------------------------------------------------------
__device__ __forceinline__ void wtrans_one(
    const float* __restrict__ w, const float* __restrict__ bias,
    _Float16* __restrict__ wA, float* __restrict__ bA,
    int CO_PAD, int CIN, int CG, int idx, int nwA)
{
    if (idx < nwA) {
        int t = idx / (CO_PAD * 32);
        int rem = idx - t * (CO_PAD * 32);
        int cop = rem >> 5;
        int k = rem & 31;
        int cell = cop >> 2, gate = cop & 3;
        float v = 0.f;
        if (k < CIN && cell < CG)
            v = w[((gate * CG + cell) * CIN + k) * 9 + t];
        wA[idx] = (_Float16)v;
    } else {
        int cop = idx - nwA;           // < CO_PAD
        int cell = cop >> 2, gate = cop & 3;
        bA[cop] = (cell < CG) ? bias[gate * CG + cell] : 0.f;
    }
}

#define WA1_N (9 * 32 * 32)   // 9216
#define WA2_N (9 * 64 * 32)   // 18432
#define WA3_N (9 * 16 * 32)   // 4608

__global__ __launch_bounds__(256) void wtrans_kernel(
    const float* __restrict__ w1, const float* __restrict__ b1,
    const float* __restrict__ w2, const float* __restrict__ b2,
    const float* __restrict__ w3, const float* __restrict__ b3,
    _Float16* __restrict__ wA1, _Float16* __restrict__ wA2,
    _Float16* __restrict__ wA3,
    float* __restrict__ bA1, float* __restrict__ bA2, float* __restrict__ bA3)
{
    int idx = blockIdx.x * 256 + threadIdx.x;
    if (idx < WA1_N + 32)
        wtrans_one(w1, b1, wA1, bA1, 32, 11, 8, idx, WA1_N);
    else if (idx < WA1_N + 32 + WA2_N + 64)
        wtrans_one(w2, b2, wA2, bA2, 64, 24, 16, idx - (WA1_N + 32), WA2_N);
    else if (idx < WA1_N + 32 + WA2_N + 64 + WA3_N + 16)
        wtrans_one(w3, b3, wA3, bA3, 16, 19, 3, idx - (WA1_N + 32 + WA2_N + 64), WA3_N);
}

// ---------------------------------------------------------------------------
// 1. mask kernel: fovea = x * ((rand>0.95)|patch), hr = x * patch
// ---------------------------------------------------------------------------
__global__ __launch_bounds__(256) void mask_kernel(
    const float* __restrict__ x,
    const float* __restrict__ rmask,
    const int* __restrict__ samples,
    float* __restrict__ fovea,
    float* __restrict__ hr)
{
    int idx = blockIdx.x * 256 + threadIdx.x;          // b*S + p
    if (idx >= BB * SS) return;
    int b = idx / SS;
    int p = idx - b * SS;
    int y = p / NN;
    int xx = p - y * NN;
    int s = samples[b];
    int px = s / 7, py = s - px * 7;
    bool patch = (y >= px * 32) && (y < px * 32 + 32) &&
                 (xx >= py * 32) && (xx < py * 32 + 32);
    bool m = (rmask[idx] > 0.95f) || patch;
#pragma unroll
    for (int c = 0; c < 3; ++c) {
        size_t o = ((size_t)b * 3 + c) * SS + p;
        float xv = x[o];
        fovea[o] = m ? xv : 0.f;
        hr[o]    = patch ? xv : 0.f;
    }
}

// ---------------------------------------------------------------------------
// 2-4. ConvLSTM (MFMA): z = conv3x3([xin,hin])+b ; gates ; (h,c) out
// Block: 32x8 px, 256 thr (4 waves). Wave owns 4 pix-tiles x CT co-tiles.
// ---------------------------------------------------------------------------
template <int CIN1, int CIN2, int CG, int CO_PAD>
__global__ __launch_bounds__(256, 4) void convlstm_mfma(
    const float* __restrict__ xin,
    const float* __restrict__ hin,
    const float* __restrict__ cin,
    const _Float16* __restrict__ wA,   // [9][CO_PAD][32] f16
    const float* __restrict__ bA,      // [CO_PAD] gate-interleaved
    float* __restrict__ hout,
    float* __restrict__ cout_,
    float* __restrict__ hout2)
{
    constexpr int CIN = CIN1 + CIN2;
    constexpr int CT = CO_PAD / 16;    // co-tiles

    __shared__ h8 lds8[4 * HPIX];      // [kb][pix] of 8 f16 = 21760 B

    const int tid = threadIdx.x;
    const int tileId = blockIdx.x;     // 0..195 (7 x-tiles, 28 y-tiles)
    const int tx0 = (tileId % 7) * TWL;
    const int ty0 = (tileId / 7) * THL;
    const int b = blockIdx.y;

    // ---- stage halo tile as f16, channel-last k-blocked; zero-pad k>=CIN ----
    _Float16* ldsh = (_Float16*)lds8;
    for (int idx = tid; idx < 32 * HPIX; idx += 256) {
        int ci = idx / HPIX;           // 0..31 (incl. zero-pad channels)
        int p = idx - ci * HPIX;
        int row = p / 34;              // 0..9
        int col = p - row * 34;
        int gy = ty0 + row - 1;
        int gx = tx0 + col - 1;
        float v = 0.f;
        if (ci < CIN && (unsigned)gy < NN && (unsigned)gx < NN) {
            const float* src = (ci < CIN1)
                ? xin + ((size_t)b * CIN1 + ci) * SS
                : hin + ((size_t)b * CIN2 + (ci - CIN1)) * SS;
            v = src[gy * NN + gx];
        }
        ldsh[((ci >> 3) * HPIX + p) * 8 + (ci & 7)] = (_Float16)v;
    }
    __syncthreads();

    const int lane = tid & 63;
    const int wid = tid >> 6;
    const int l15 = lane & 15;         // pixel-in-tile / D column
    const int kb = lane >> 4;          // k-block / D row-group

    // bias vectors (co' = ct*16 + kb*4 + reg)
    f4 acc[4][CT];
#pragma unroll
    for (int ct = 0; ct < CT; ++ct) {
        f4 bv = *reinterpret_cast<const f4*>(&bA[ct * 16 + kb * 4]);
#pragma unroll
        for (int pt = 0; pt < 4; ++pt)
            acc[pt][ct] = bv;
    }

    // per-pix-tile LDS h8-base: kb*HPIX + r*34 + h*16 + l15 (pg = wid*4+pt)
    int pbase[4];
#pragma unroll
    for (int pt = 0; pt < 4; ++pt) {
        int pg = wid * 4 + pt;
        int r = pg >> 1, h = pg & 1;
        pbase[pt] = kb * HPIX + r * 34 + h * 16 + l15;
    }

    // ---- 9 shifted GEMMs ----
#pragma unroll 1
    for (int t = 0; t < 9; ++t) {
        int dy = (t * 11) >> 5;        // t/3 for t<9
        int dx = t - 3 * dy;
        int toff = dy * 34 + dx;

        h8 aF[CT];
#pragma unroll
        for (int ct = 0; ct < CT; ++ct)
            aF[ct] = *reinterpret_cast<const h8*>(
                wA + ((size_t)(t * CO_PAD + ct * 16 + l15)) * 32 + kb * 8);

#pragma unroll
        for (int pt = 0; pt < 4; ++pt) {
            h8 bF = lds8[pbase[pt] + toff];
#pragma unroll
            for (int ct = 0; ct < CT; ++ct)
                acc[pt][ct] = __builtin_amdgcn_mfma_f32_16x16x32_f16(
                    aF[ct], bF, acc[pt][ct], 0, 0, 0);
        }
    }

    // ---- gates (register-local: lane's 4 regs = i,f,o,g of one cell) ----
#pragma unroll
    for (int pt = 0; pt < 4; ++pt) {
        int pg = wid * 4 + pt;
        int r = pg >> 1, h = pg & 1;
        int gy = ty0 + r;
        int gx = tx0 + h * 16 + l15;
#pragma unroll
        for (int ct = 0; ct < CT; ++ct) {
            int cell = ct * 4 + kb;
            if (4 * CG == CO_PAD || cell < CG) {
                size_t base = ((size_t)b * CG + cell) * SS + (size_t)gy * NN + gx;
                float cv = cin[base];
                float iv = fsigmoid(acc[pt][ct][0]);
                float fv = fsigmoid(acc[pt][ct][1]);
                float ov = fsigmoid(acc[pt][ct][2]);
                float gv = ftanh(acc[pt][ct][3]);
                float cn = fv * cv + iv * gv;
                float hv = ov * ftanh(cn);
                cout_[base] = cn;
                hout[base] = hv;
                if (hout2) hout2[base] = hv;
            }
        }
    }
}

// ---------------------------------------------------------------------------
// 5. plain 3x3 conv (reconstruction): 3 -> 3 channels (VALU, unchanged)
// ---------------------------------------------------------------------------
__global__ __launch_bounds__(256) void conv_plain_kernel(
    const float* __restrict__ in,
    const float* __restrict__ w,      // [3][3][3][3]
    const float* __restrict__ bias,   // [3]
    float* __restrict__ out)
{
    constexpr int CIN = 3, NCO = 3;
    __shared__ float lds[CIN * LDS_CS];

    const int tid = threadIdx.x;
    const int tileId = blockIdx.x;
    const int tx0 = (tileId % 7) * TW;
    const int ty0 = (tileId / 7) * TH;
    const int b = blockIdx.y;

    const int TOT = CIN * 18 * 34;
    for (int idx = tid; idx < TOT; idx += 256) {
        int ci = idx / (18 * 34);
        int r = idx - ci * (18 * 34);
        int row = r / 34;
        int col = r - row * 34;
        int gy = ty0 + row - 1;
        int gx = tx0 + col - 1;
        float v = 0.f;
        if ((unsigned)gy < NN && (unsigned)gx < NN)
            v = in[((size_t)b * CIN + ci) * SS + gy * NN + gx];
        lds[ci * LDS_CS + row * LDS_RS + col] = v;
    }
    __syncthreads();

    const int tx2 = tid & 15;
    const int ty = tid >> 4;
    const int lx = 2 * tx2;

    float accx[NCO], accy[NCO];
#pragma unroll
    for (int g = 0; g < NCO; ++g) { accx[g] = bias[g]; accy[g] = bias[g]; }

#pragma unroll
    for (int ci = 0; ci < CIN; ++ci) {
        float n[3][4];
        const float* lrow = &lds[ci * LDS_CS + ty * LDS_RS + lx];
#pragma unroll
        for (int dy = 0; dy < 3; ++dy)
#pragma unroll
            for (int dx = 0; dx < 4; ++dx)
                n[dy][dx] = lrow[dy * LDS_RS + dx];
#pragma unroll
        for (int g = 0; g < NCO; ++g) {
            const float* wr = &w[((size_t)g * CIN + ci) * 9];
            float ax = accx[g], ay = accy[g];
#pragma unroll
            for (int dy = 0; dy < 3; ++dy)
#pragma unroll
                for (int dx = 0; dx < 3; ++dx) {
                    float wv = wr[dy * 3 + dx];
                    ax += wv * n[dy][dx];
                    ay += wv * n[dy][dx + 1];
                }
            accx[g] = ax;
            accy[g] = ay;
        }
    }

    const int gy = ty0 + ty;
    const int gx = tx0 + lx;
#pragma unroll
    for (int g = 0; g < NCO; ++g) {
        size_t base = ((size_t)b * NCO + g) * SS + (size_t)gy * NN + gx;
        store_f2(&out[base], accx[g], accy[g]);
    }
}

// ---------------------------------------------------------------------------
extern "C" void kernel_launch(void* const* d_in, const int* in_sizes, int n_in,
                              void* d_out, int out_size, void* d_ws, size_t ws_size,
                              hipStream_t stream)
{
    (void)in_sizes; (void)n_in; (void)out_size; (void)ws_size;

    const float* x     = (const float*)d_in[0];
    const float* h1    = (const float*)d_in[2];
    const float* c1    = (const float*)d_in[3];
    const float* h2    = (const float*)d_in[4];
    const float* c2    = (const float*)d_in[5];
    const float* h3    = (const float*)d_in[6];
    const float* c3    = (const float*)d_in[7];
    const float* rmask = (const float*)d_in[8];
    const int* samples = (const int*)d_in[9];
    const float* W1    = (const float*)d_in[10];
    const float* B1    = (const float*)d_in[11];
    const float* W2    = (const float*)d_in[12];
    const float* B2    = (const float*)d_in[13];
    const float* W3    = (const float*)d_in[14];
    const float* B3    = (const float*)d_in[15];
    const float* WC    = (const float*)d_in[16];
    const float* BC    = (const float*)d_in[17];

    float* out = (float*)d_out;
    // output offsets (elements, reference return order)
    float* h1n    = out + 0;
    float* c1n    = out + 12845056;
    float* h2n    = out + 25690112;
    float* c2n    = out + 51380224;
    float* h3n    = out + 77070336;
    float* c3n    = out + 81887232;
    float* recon  = out + 86704128;
    float* fovea  = out + 91521024;
    float* hr     = out + 96337920;
    float* hidden = out + 101154816;

    // workspace: packed f16 A-fragments + gate-interleaved biases
    _Float16* wsh = (_Float16*)d_ws;
    _Float16* wA1 = wsh;                         // 9216 f16
    _Float16* wA2 = wsh + WA1_N;                 // 18432 f16
    _Float16* wA3 = wsh + WA1_N + WA2_N;         // 4608 f16
    float* bAall  = (float*)(wsh + WA1_N + WA2_N + WA3_N);  // 16B-aligned
    float* bA1 = bAall;        // 32 f32
    float* bA2 = bAall + 32;   // 64 f32
    float* bA3 = bAall + 96;   // 16 f32

    const int WT_TOT = WA1_N + 32 + WA2_N + 64 + WA3_N + 16;   // 32368
    wtrans_kernel<<<(WT_TOT + 255) / 256, 256, 0, stream>>>(
        W1, B1, W2, B2, W3, B3, wA1, wA2, wA3, bA1, bA2, bA3);

    mask_kernel<<<(BB * SS + 255) / 256, 256, 0, stream>>>(x, rmask, samples, fovea, hr);

    // grid: 196 tiles (7x * 28y) x 32 batch
    convlstm_mfma<3, 8, 8, 32><<<dim3(196, BB), 256, 0, stream>>>(
        fovea, h1, c1, wA1, bA1, h1n, c1n, nullptr);

    convlstm_mfma<8, 16, 16, 64><<<dim3(196, BB), 256, 0, stream>>>(
        h1n, h2, c2, wA2, bA2, h2n, c2n, nullptr);

    convlstm_mfma<16, 3, 3, 16><<<dim3(196, BB), 256, 0, stream>>>(
        h2n, h3, c3, wA3, bA3, h3n, c3n, hidden);

    conv_plain_kernel<<<dim3(98, BB, 1), 256, 0, stream>>>(h3n, WC, BC, recon);
}